// Round 14
// baseline (494.199 us; speedup 1.0000x reference)
//
#include <hip/hip_runtime.h>

#define NN 100000
#define NE 1600000
#define NG 128
#define BN_EPS 1e-5f
#define NBKT 64
#define AGG_BLOCKS 2048
#define AGG_WAVES (AGG_BLOCKS * 4)
#define NBUCK 98          // ceil(NN / 1024)
#define BIN_BLOCKS 256
#define BIN_CHUNK 6250    // NE / BIN_BLOCKS exact

typedef short s16x8 __attribute__((ext_vector_type(8)));
typedef float f32x4 __attribute__((ext_vector_type(4)));

static __device__ __forceinline__ unsigned short f2bf(float f) {
    unsigned u = __float_as_uint(f);
    u += 0x7fffu + ((u >> 16) & 1u);   // RNE
    return (unsigned short)(u >> 16);
}
static __device__ __forceinline__ unsigned packbf(float a, float b) {
    return (unsigned)f2bf(a) | ((unsigned)f2bf(b) << 16);
}
static __device__ __forceinline__ float bf_lo(unsigned u) { return __uint_as_float(u << 16); }
static __device__ __forceinline__ float bf_hi(unsigned u) { return __uint_as_float(u & 0xffff0000u); }
static __device__ __forceinline__ float bf2f(ushort u) { return __uint_as_float((unsigned)u << 16); }

// ---------------- setup: W fragments + all zeroing ----------------
__global__ __launch_bounds__(256) void k_setup(const float* __restrict__ W0, const float* __restrict__ W1,
                                               const float* __restrict__ W2, ushort* __restrict__ Wf,
                                               int* __restrict__ gbh, int* __restrict__ ticks,
                                               float* __restrict__ bnst, float* __restrict__ gout,
                                               uint* __restrict__ hmz) {
    int b = blockIdx.x, t = threadIdx.x;
    if (b < 96) {
        if (t >= 64) return;
        int layer = b >> 5, unit = b & 31;
        const float* W = (layer == 0) ? W0 : ((layer == 1) ? W1 : W2);
        int ks = unit >> 3, nb = unit & 7;
        int n = nb * 16 + (t & 15);
        int k0 = ks * 32 + (t >> 4) * 8;
        ushort o[8];
#pragma unroll
        for (int j = 0; j < 8; ++j) o[j] = f2bf(W[(size_t)(k0 + j) * 128 + n]);
        ushort* p = Wf + (size_t)layer * 16384 + ((size_t)unit * 64 + t) * 8;
#pragma unroll
        for (int j = 0; j < 8; ++j) p[j] = o[j];
    } else {
        int gid = (b - 96) * 256 + t;
        if (gid < 49152) bnst[gid] = 0.f;
        else if (gid < 98304) gout[gid - 49152] = 0.f;
        else if (gid < 98432) gbh[gid - 98304] = 0;
        else if (gid < 98440) ticks[gid - 98432] = 0;
        else if (gid < 98504) hmz[gid - 98440] = 0u;
    }
}

// ---------------- coarse bucket histogram + fused scan (last-block ticket) ----------------
__global__ __launch_bounds__(256) void k_bhist(const int* __restrict__ dst, int* __restrict__ gbh,
                                               int* __restrict__ gbase, int* __restrict__ gcur,
                                               int* __restrict__ row_start, int* __restrict__ tick) {
    __shared__ int lh[128], sbuf[128];
    __shared__ int isLast;
    int t = threadIdx.x;
    if (t < 128) lh[t] = 0;
    __syncthreads();
    for (int e = blockIdx.x * 256 + t; e < NE; e += gridDim.x * 256)
        atomicAdd(&lh[dst[e] >> 10], 1);
    __syncthreads();
    if (t < 128 && lh[t]) atomicAdd(&gbh[t], lh[t]);
    __threadfence();
    __syncthreads();
    if (t == 0) isLast = (atomicAdd(tick, 1) == (int)gridDim.x - 1);
    __syncthreads();
    if (!isLast) return;
    int v = 0;
    if (t < 128) { v = atomicAdd(&gbh[t], 0); sbuf[t] = v; }
    __syncthreads();
    for (int o = 1; o < 128; o <<= 1) {
        int a = (t >= o && t < 128) ? sbuf[t - o] : 0;
        __syncthreads();
        if (t < 128) sbuf[t] += a;
        __syncthreads();
    }
    if (t < 128) {
        int ex = sbuf[t] - v;
        gbase[t] = ex;
        gcur[t] = ex;
        if (t == 127) { gbase[128] = sbuf[127]; row_start[NN] = NE; }
    }
}

// ---------------- pass 1: bin edges into bucket regions ----------------
__global__ __launch_bounds__(256) void k_bin(const int* __restrict__ src, const int* __restrict__ dst,
                                             int* __restrict__ gcur, int* __restrict__ tmp) {
    __shared__ int lh[128], lb[128], lc[128];
    int t = threadIdx.x;
    if (t < 128) lh[t] = 0;
    __syncthreads();
    int e0 = blockIdx.x * BIN_CHUNK, e1 = e0 + BIN_CHUNK;
    for (int e = e0 + t; e < e1; e += 256) atomicAdd(&lh[dst[e] >> 10], 1);
    __syncthreads();
    if (t < 128) {
        int c = lh[t];
        lb[t] = c ? atomicAdd(&gcur[t], c) : 0;
        lc[t] = 0;
    }
    __syncthreads();
    for (int e = e0 + t; e < e1; e += 256) {
        int d = dst[e];
        int b = d >> 10;
        int off = atomicAdd(&lc[b], 1);
        tmp[lb[b] + off] = (src[e] << 10) | (d & 1023);   // src:17b | dst_lo:10b
    }
}

// ---------------- pass 2: per-bucket counting sort -> esrc, row_start, dinv ----------------
__global__ __launch_bounds__(256) void k_csr(const int* __restrict__ tmp, const int* __restrict__ gbase,
                                             int* __restrict__ esrc, int* __restrict__ row_start,
                                             float* __restrict__ dinv) {
    __shared__ int h[1024], hs[1024], part[256];
    int b = blockIdx.x, t = threadIdx.x;
    int base = gbase[b], end = gbase[b + 1];
#pragma unroll
    for (int k = 0; k < 4; ++k) h[t * 4 + k] = 0;
    __syncthreads();
    for (int i = base + t; i < end; i += 256) atomicAdd(&h[tmp[i] & 1023], 1);
    __syncthreads();
    int l0 = h[t * 4], l1 = h[t * 4 + 1], l2 = h[t * 4 + 2], l3 = h[t * 4 + 3];
    int ssum = l0 + l1 + l2 + l3;
    part[t] = ssum;
    __syncthreads();
    for (int o = 1; o < 256; o <<= 1) {
        int a = (t >= o) ? part[t - o] : 0;
        __syncthreads();
        part[t] += a;
        __syncthreads();
    }
    int ex = part[t] - ssum;
    hs[t * 4]     = ex;
    hs[t * 4 + 1] = ex + l0;
    hs[t * 4 + 2] = ex + l0 + l1;
    hs[t * 4 + 3] = ex + l0 + l1 + l2;
    int n0 = b * 1024 + t * 4;
#pragma unroll
    for (int k = 0; k < 4; ++k) {
        int n = n0 + k;
        if (n < NN) {
            row_start[n] = base + hs[t * 4 + k];
            dinv[n] = rsqrtf((float)h[t * 4 + k] + 1.0f);
        }
    }
    __syncthreads();
    for (int i = base + t; i < end; i += 256) {
        int rec = tmp[i];
        int pos = atomicAdd(&hs[rec & 1023], 1);
        esrc[base + pos] = rec >> 10;
    }
}

// ---------------- merged: BN finalize (block 0) + W-scale for next layer (blocks 1..32) ----------------
__global__ __launch_bounds__(128) void k_finwscale(const float* __restrict__ S, const float* __restrict__ Q,
                                                   const float* __restrict__ gam, const float* __restrict__ bet,
                                                   float* __restrict__ svec, float* __restrict__ tvec,
                                                   const float* __restrict__ Wnext, float* __restrict__ tW,
                                                   const ushort* __restrict__ Wfb, ushort* __restrict__ Wff) {
    int bid = blockIdx.x;
    int t = threadIdx.x;
    if (bid == 0) {
        __shared__ float ts[128];
        float s = 0.f, q = 0.f;
        for (int k = 0; k < NBKT; ++k) {
            s += S[k * 128 + t];
            q += Q[k * 128 + t];
        }
        float mean = s / (float)NN;
        float var = q / (float)NN - mean * mean;
        float rstd = rsqrtf(fmaxf(var, 0.f) + BN_EPS);
        float sc = gam[t] * rstd;
        float sh = bet[t] - mean * sc;
        svec[t] = sc;
        tvec[t] = sh;
        ts[t] = sh;
        __syncthreads();
        if (Wnext) {
            float acc = 0.f;
            for (int k = 0; k < 128; ++k) acc += ts[k] * Wnext[(size_t)k * 128 + t];
            tW[t] = acc;
        }
    } else {
        __shared__ float sv[32];
        int unit = bid - 1;
        int kbase = (unit >> 3) * 32;
        if (t < 32) {
            int c = kbase + t;
            float s = 0.f, q = 0.f;
            for (int k = 0; k < NBKT; ++k) {
                s += S[k * 128 + c];
                q += Q[k * 128 + c];
            }
            float mean = s / (float)NN;
            float var = q / (float)NN - mean * mean;
            sv[t] = gam[c] * rsqrtf(fmaxf(var, 0.f) + BN_EPS);
        }
        __syncthreads();
        if (t < 64) {
            int ko = (t >> 4) * 8;
            const ushort* p = Wfb + ((size_t)unit * 64 + t) * 8;
            ushort* o = Wff + ((size_t)unit * 64 + t) * 8;
#pragma unroll
            for (int j = 0; j < 8; ++j) o[j] = f2bf(bf2f(p[j]) * sv[ko + j]);
        }
    }
}

// ---------------- MFMA GEMM (pure): hm'[N][128] = dinv[row] * (X @ Wf + tW) ----------------
__global__ __launch_bounds__(256) void k_gemm(const ushort* __restrict__ Xb, const float* __restrict__ xf32,
                                              const ushort* __restrict__ Wf, const float* __restrict__ tW,
                                              const float* __restrict__ dinv, ushort* __restrict__ hm) {
    int tid = threadIdx.x;
    int wid = tid >> 6, lane = tid & 63;
    int r0 = blockIdx.x * 64 + wid * 16;
    int m = lane & 15, g = lane >> 4;
    int xrow = r0 + m;
    int xr = (xrow < NN) ? xrow : (NN - 1);
    s16x8 af[4];
    if (xf32) {
        const float* Xr = xf32 + (size_t)xr * 128 + g * 8;
#pragma unroll
        for (int ks = 0; ks < 4; ++ks) {
            float4 a = *(const float4*)(Xr + ks * 32);
            float4 b = *(const float4*)(Xr + ks * 32 + 4);
            s16x8 v;
            v[0] = (short)f2bf(a.x); v[1] = (short)f2bf(a.y);
            v[2] = (short)f2bf(a.z); v[3] = (short)f2bf(a.w);
            v[4] = (short)f2bf(b.x); v[5] = (short)f2bf(b.y);
            v[6] = (short)f2bf(b.z); v[7] = (short)f2bf(b.w);
            af[ks] = v;
        }
    } else {
        const ushort* Xrow = Xb + (size_t)xr * 128 + g * 8;
#pragma unroll
        for (int ks = 0; ks < 4; ++ks) af[ks] = *(const s16x8*)(Xrow + ks * 32);
    }
    f32x4 acc[8];
#pragma unroll
    for (int nb = 0; nb < 8; ++nb) acc[nb] = (f32x4){0.f, 0.f, 0.f, 0.f};
#pragma unroll
    for (int ks = 0; ks < 4; ++ks) {
#pragma unroll
        for (int nb = 0; nb < 8; ++nb) {
            s16x8 wf = *(const s16x8*)(Wf + ((size_t)(ks * 8 + nb) * 64 + lane) * 8);
            acc[nb] = __builtin_amdgcn_mfma_f32_16x16x32_bf16(wf, af[ks], acc[nb], 0, 0, 0);
        }
    }
    if (xrow < NN) {
        float ds = dinv[xr];
        ushort* orow = hm + (size_t)xrow * 128 + g * 4;
        if (tW) {
#pragma unroll
            for (int nb = 0; nb < 8; ++nb) {
                float4 tw = *(const float4*)(tW + nb * 16 + g * 4);
                ushort4 o;
                o.x = f2bf(ds * (acc[nb][0] + tw.x));
                o.y = f2bf(ds * (acc[nb][1] + tw.y));
                o.z = f2bf(ds * (acc[nb][2] + tw.z));
                o.w = f2bf(ds * (acc[nb][3] + tw.w));
                *(ushort4*)(orow + nb * 16) = o;
            }
        } else {
#pragma unroll
            for (int nb = 0; nb < 8; ++nb) {
                ushort4 o;
                o.x = f2bf(ds * acc[nb][0]);
                o.y = f2bf(ds * acc[nb][1]);
                o.z = f2bf(ds * acc[nb][2]);
                o.w = f2bf(ds * acc[nb][3]);
                *(ushort4*)(orow + nb * 16) = o;
            }
        }
    }
}

// ---------------- aggregate: dwordx2 gathers, 2 rows per instruction ----------------
// half 0 (lanes 0-31) covers even edges, half 1 odd edges. Lane handles channels 4c..4c+3
// (c = lane&31, 8B per lane -> each half reads one full 256B row per instruction).
// Combine via shfl(lane^32) at the end; lanes 0-31 write act + stats.
__global__ __launch_bounds__(256) void k_agg(const uint2* __restrict__ hm64, const int* __restrict__ esrc,
                                             const int* __restrict__ rs, const float* __restrict__ dinv,
                                             const float* __restrict__ bias, uint2* __restrict__ act,
                                             float* __restrict__ bnsum, float* __restrict__ bnsq) {
    __shared__ float ls[128], lq[128];
    int tid = threadIdx.x;
    if (tid < 128) { ls[tid] = 0.f; lq[tid] = 0.f; }
    __syncthreads();
    int lane = tid & 63;
    int half = lane >> 5;
    int c = lane & 31;                 // channel-quad index
    int wgid = blockIdx.x * 4 + (tid >> 6);
    float4 b4 = *(const float4*)(bias + c * 4);
    float st0 = 0.f, st1 = 0.f, st2 = 0.f, st3 = 0.f;
    float sq0 = 0.f, sq1 = 0.f, sq2 = 0.f, sq3 = 0.f;

    for (int n = wgid; n < NN; n += AGG_WAVES) {
        int selfidx = half ? NN : n;   // half 1 reads the zero row
        uint2 sv = hm64[(size_t)selfidx * 32 + c];
        float a0 = bf_lo(sv.x), a1 = bf_hi(sv.x);
        float a2 = bf_lo(sv.y), a3 = bf_hi(sv.y);

        int i  = __builtin_amdgcn_readfirstlane(rs[n]);
        int i1 = __builtin_amdgcn_readfirstlane(rs[n + 1]);

        int idxv = 0;
        if (i < i1) idxv = esrc[i + min(c, i1 - i - 1)];

        while (i < i1) {
            int cnt = i1 - i;
            cnt = (cnt > 32) ? 32 : cnt;       // wave-uniform
            int cur = idxv;
            int inext = i + cnt;
            if (inext < i1)                    // prefetch next 32 indices while gathers fly
                idxv = esrc[inext + min(c, i1 - inext - 1)];
            uint2 g[16];
#pragma unroll
            for (int u = 0; u < 16; ++u) {
                int ia = __builtin_amdgcn_readlane(cur, 2 * u);
                int ib = __builtin_amdgcn_readlane(cur, 2 * u + 1);
                ia = (2 * u < cnt) ? ia : NN;          // scalar selects (pads -> zero row)
                ib = (2 * u + 1 < cnt) ? ib : NN;
                int sidx = half ? ib : ia;             // per-lane half select
                g[u] = hm64[(size_t)sidx * 32 + c];
            }
#pragma unroll
            for (int u = 0; u < 16; ++u) {
                a0 += bf_lo(g[u].x); a1 += bf_hi(g[u].x);
                a2 += bf_lo(g[u].y); a3 += bf_hi(g[u].y);
            }
            i = inext;
        }
        // combine even/odd halves: partner lane ^ 32 holds the other parity's sums
        a0 += __shfl(a0, lane ^ 32);
        a1 += __shfl(a1, lane ^ 32);
        a2 += __shfl(a2, lane ^ 32);
        a3 += __shfl(a3, lane ^ 32);
        if (!half) {
            float di = dinv[n];
            float z0 = fmaxf(fmaf(di, a0, b4.x), 0.f);
            float z1 = fmaxf(fmaf(di, a1, b4.y), 0.f);
            float z2 = fmaxf(fmaf(di, a2, b4.z), 0.f);
            float z3 = fmaxf(fmaf(di, a3, b4.w), 0.f);
            act[(size_t)n * 32 + c] = make_uint2(packbf(z0, z1), packbf(z2, z3));
            st0 += z0; st1 += z1; st2 += z2; st3 += z3;
            sq0 += z0 * z0; sq1 += z1 * z1; sq2 += z2 * z2; sq3 += z3 * z3;
        }
    }
    if (!half) {
        atomicAdd(&ls[c * 4 + 0], st0);
        atomicAdd(&ls[c * 4 + 1], st1);
        atomicAdd(&ls[c * 4 + 2], st2);
        atomicAdd(&ls[c * 4 + 3], st3);
        atomicAdd(&lq[c * 4 + 0], sq0);
        atomicAdd(&lq[c * 4 + 1], sq1);
        atomicAdd(&lq[c * 4 + 2], sq2);
        atomicAdd(&lq[c * 4 + 3], sq3);
    }
    __syncthreads();
    if (tid < 128) {
        int bkt = blockIdx.x & (NBKT - 1);
        atomicAdd(&bnsum[bkt * 128 + tid], ls[tid]);
        atomicAdd(&bnsq[bkt * 128 + tid],  lq[tid]);
    }
}

// ---------------- per-graph pool + h_cat out-write ----------------
__global__ __launch_bounds__(128) void k_pool(const uint* __restrict__ act32, const float* __restrict__ svec,
                                              const float* __restrict__ tvec, const int* __restrict__ batch,
                                              float* __restrict__ gout, float* __restrict__ outp, int lofs) {
    int t = threadIdx.x;
    int lane = t & 63;
    int w = t >> 6;
    int n0 = blockIdx.x * 64;
    float sc0 = svec[lane * 2], sc1 = svec[lane * 2 + 1];
    float sh0 = tvec[lane * 2], sh1 = tvec[lane * 2 + 1];
    float s0 = 0.f, s1 = 0.f;
    int cnt = 0, curg = -1;
    for (int k = w; k < 64; k += 2) {
        int n = n0 + k;
        if (n >= NN) break;
        int gn = batch[n];
        if (gn != curg) {
            if (cnt) {
                atomicAdd(&gout[(size_t)curg * 384 + lofs + lane * 2],     sc0 * s0 + sh0 * (float)cnt);
                atomicAdd(&gout[(size_t)curg * 384 + lofs + lane * 2 + 1], sc1 * s1 + sh1 * (float)cnt);
            }
            curg = gn; s0 = 0.f; s1 = 0.f; cnt = 0;
        }
        uint v = act32[(size_t)n * 64 + lane];
        float a0 = bf_lo(v), a1 = bf_hi(v);
        float2 z;
        z.x = a0 * sc0 + sh0;
        z.y = a1 * sc1 + sh1;
        *(float2*)(outp + (size_t)n * 384 + lofs + lane * 2) = z;
        s0 += a0;
        s1 += a1;
        ++cnt;
    }
    if (cnt) {
        atomicAdd(&gout[(size_t)curg * 384 + lofs + lane * 2],     sc0 * s0 + sh0 * (float)cnt);
        atomicAdd(&gout[(size_t)curg * 384 + lofs + lane * 2 + 1], sc1 * s1 + sh1 * (float)cnt);
    }
}

extern "C" void kernel_launch(void* const* d_in, const int* in_sizes, int n_in,
                              void* d_out, int out_size, void* d_ws, size_t ws_size,
                              hipStream_t stream) {
    const float* x = (const float*)d_in[0];
    const int* ei = (const int*)d_in[1];
    const int* src = ei;
    const int* dst = ei + NE;
    const int* batch = (const int*)d_in[2];
    const float *W[3], *b[3], *g[3], *beta[3];
    for (int l = 0; l < 3; ++l) {
        W[l]    = (const float*)d_in[3 + 4 * l];
        b[l]    = (const float*)d_in[4 + 4 * l];
        g[l]    = (const float*)d_in[5 + 4 * l];
        beta[l] = (const float*)d_in[6 + 4 * l];
    }
    float* out = (float*)d_out;
    float* gout = out + (size_t)NN * 384;

    char* ws = (char*)d_ws;
    size_t off = 0;
    auto alloc = [&](size_t bytes) -> char* {
        off = (off + 255) & ~(size_t)255;
        char* p = ws + off;
        off += bytes;
        return p;
    };
    ushort* act      = (ushort*)alloc((size_t)NN * 256);        // bf16 relu output (pre-BN)
    ushort* hm       = (ushort*)alloc((size_t)(NN + 1) * 256);  // bf16 hm' rows + zero row at NN
    int*    esrc     = (int*)alloc((size_t)NE * 4);
    int*    tmp      = (int*)alloc((size_t)NE * 4);
    int*    row_start= (int*)alloc((size_t)(NN + 1) * 4);
    float*  dinv     = (float*)alloc((size_t)NN * 4);
    float*  bnst     = (float*)alloc((size_t)3 * 2 * NBKT * 128 * 4);   // [layer][sum|sq][NBKT][128]
    ushort* Wf       = (ushort*)alloc(3 * 16384 * 2);
    ushort* Wff      = (ushort*)alloc(16384 * 2);
    float*  svt      = (float*)alloc(3 * 2 * 128 * 4);                  // [layer][s|t][128]
    float*  tW       = (float*)alloc(128 * 4);
    int*    misc     = (int*)alloc(1024 * 4);   // gbh[128], gbase[129], gcur[128], ticks[8]
    int* gbh   = misc;
    int* gbase = misc + 128;
    int* gcur  = misc + 384;
    int* ticks = misc + 512;
    uint* hmz  = (uint*)(hm + (size_t)NN * 128);
    (void)ws_size;

    // 16 dispatches, no memsets
    k_setup<<<481, 256, 0, stream>>>(W[0], W[1], W[2], Wf, gbh, ticks, bnst, gout, hmz);
    k_bhist<<<512, 256, 0, stream>>>(dst, gbh, gbase, gcur, row_start, ticks);
    k_bin<<<BIN_BLOCKS, 256, 0, stream>>>(src, dst, gcur, tmp);
    k_csr<<<NBUCK, 256, 0, stream>>>(tmp, gbase, esrc, row_start, dinv);

    for (int l = 0; l < 3; ++l) {
        float* S = bnst + (size_t)l * 2 * NBKT * 128;
        float* Q = S + NBKT * 128;
        float* sv = svt + l * 256;
        float* tv = sv + 128;
        const ushort* gin = (l == 0) ? (const ushort*)nullptr : act;
        const float* xin = (l == 0) ? x : nullptr;
        const ushort* wfrag = (l == 0) ? (Wf + 0) : Wff;
        const float* tw_in = (l == 0) ? nullptr : tW;
        const float* wnp = (l < 2) ? W[l + 1] : nullptr;
        const ushort* wfbp = (l < 2) ? (Wf + (size_t)(l + 1) * 16384) : nullptr;

        k_gemm<<<(NN + 63) / 64, 256, 0, stream>>>(gin, xin, wfrag, tw_in, dinv, hm);
        k_agg<<<AGG_BLOCKS, 256, 0, stream>>>((const uint2*)hm, esrc, row_start, dinv, b[l],
                                              (uint2*)act, S, Q);
        k_finwscale<<<(l < 2) ? 33 : 1, 128, 0, stream>>>(S, Q, g[l], beta[l], sv, tv,
                                                          wnp, tW, wfbp, Wff);
        k_pool<<<(NN + 63) / 64, 128, 0, stream>>>((const uint*)act, sv, tv, batch, gout, out, l * 128);
    }
}

// Round 15
// 474.838 us; speedup vs baseline: 1.0408x; 1.0408x over previous
//
#include <hip/hip_runtime.h>

#define NN 100000
#define NE 1600000
#define NG 128
#define BN_EPS 1e-5f
#define NBKT 64
#define AGG_BLOCKS 2048
#define AGG_WAVES (AGG_BLOCKS * 4)
#define NBUCK 98          // ceil(NN / 1024)
#define BIN_BLOCKS 256
#define BIN_CHUNK 6250    // NE / BIN_BLOCKS exact

typedef short s16x8 __attribute__((ext_vector_type(8)));
typedef float f32x4 __attribute__((ext_vector_type(4)));

static __device__ __forceinline__ unsigned short f2bf(float f) {
    unsigned u = __float_as_uint(f);
    u += 0x7fffu + ((u >> 16) & 1u);   // RNE
    return (unsigned short)(u >> 16);
}
static __device__ __forceinline__ unsigned packbf(float a, float b) {
    return (unsigned)f2bf(a) | ((unsigned)f2bf(b) << 16);
}
static __device__ __forceinline__ float bf_lo(unsigned u) { return __uint_as_float(u << 16); }
static __device__ __forceinline__ float bf_hi(unsigned u) { return __uint_as_float(u & 0xffff0000u); }
static __device__ __forceinline__ float bf2f(ushort u) { return __uint_as_float((unsigned)u << 16); }

// ---------------- setup: W fragments + all zeroing (replaces 4 memsets + wfrag) ----------------
__global__ __launch_bounds__(256) void k_setup(const float* __restrict__ W0, const float* __restrict__ W1,
                                               const float* __restrict__ W2, ushort* __restrict__ Wf,
                                               int* __restrict__ gbh, int* __restrict__ ticks,
                                               float* __restrict__ bnst, float* __restrict__ gout,
                                               uint* __restrict__ hmz) {
    int b = blockIdx.x, t = threadIdx.x;
    if (b < 96) {
        if (t >= 64) return;
        int layer = b >> 5, unit = b & 31;
        const float* W = (layer == 0) ? W0 : ((layer == 1) ? W1 : W2);
        int ks = unit >> 3, nb = unit & 7;
        int n = nb * 16 + (t & 15);
        int k0 = ks * 32 + (t >> 4) * 8;
        ushort o[8];
#pragma unroll
        for (int j = 0; j < 8; ++j) o[j] = f2bf(W[(size_t)(k0 + j) * 128 + n]);
        ushort* p = Wf + (size_t)layer * 16384 + ((size_t)unit * 64 + t) * 8;
#pragma unroll
        for (int j = 0; j < 8; ++j) p[j] = o[j];
    } else {
        int gid = (b - 96) * 256 + t;
        if (gid < 49152) bnst[gid] = 0.f;
        else if (gid < 98304) gout[gid - 49152] = 0.f;
        else if (gid < 98432) gbh[gid - 98304] = 0;
        else if (gid < 98440) ticks[gid - 98432] = 0;
        else if (gid < 98504) hmz[gid - 98440] = 0u;
    }
}

// ---------------- coarse bucket histogram + fused scan (last-block ticket) ----------------
__global__ __launch_bounds__(256) void k_bhist(const int* __restrict__ dst, int* __restrict__ gbh,
                                               int* __restrict__ gbase, int* __restrict__ gcur,
                                               int* __restrict__ row_start, int* __restrict__ tick) {
    __shared__ int lh[128], sbuf[128];
    __shared__ int isLast;
    int t = threadIdx.x;
    if (t < 128) lh[t] = 0;
    __syncthreads();
    for (int e = blockIdx.x * 256 + t; e < NE; e += gridDim.x * 256)
        atomicAdd(&lh[dst[e] >> 10], 1);
    __syncthreads();
    if (t < 128 && lh[t]) atomicAdd(&gbh[t], lh[t]);
    __threadfence();
    __syncthreads();
    if (t == 0) isLast = (atomicAdd(tick, 1) == (int)gridDim.x - 1);
    __syncthreads();
    if (!isLast) return;
    // last block: exclusive scan of the 128 bucket counts
    int v = 0;
    if (t < 128) { v = atomicAdd(&gbh[t], 0); sbuf[t] = v; }
    __syncthreads();
    for (int o = 1; o < 128; o <<= 1) {
        int a = (t >= o && t < 128) ? sbuf[t - o] : 0;
        __syncthreads();
        if (t < 128) sbuf[t] += a;
        __syncthreads();
    }
    if (t < 128) {
        int ex = sbuf[t] - v;
        gbase[t] = ex;
        gcur[t] = ex;
        if (t == 127) { gbase[128] = sbuf[127]; row_start[NN] = NE; }
    }
}

// ---------------- pass 1: bin edges into bucket regions (time-dense writes) ----------------
__global__ __launch_bounds__(256) void k_bin(const int* __restrict__ src, const int* __restrict__ dst,
                                             int* __restrict__ gcur, int* __restrict__ tmp) {
    __shared__ int lh[128], lb[128], lc[128];
    int t = threadIdx.x;
    if (t < 128) lh[t] = 0;
    __syncthreads();
    int e0 = blockIdx.x * BIN_CHUNK, e1 = e0 + BIN_CHUNK;
    for (int e = e0 + t; e < e1; e += 256) atomicAdd(&lh[dst[e] >> 10], 1);
    __syncthreads();
    if (t < 128) {
        int c = lh[t];
        lb[t] = c ? atomicAdd(&gcur[t], c) : 0;
        lc[t] = 0;
    }
    __syncthreads();
    for (int e = e0 + t; e < e1; e += 256) {
        int d = dst[e];
        int b = d >> 10;
        int off = atomicAdd(&lc[b], 1);
        tmp[lb[b] + off] = (src[e] << 10) | (d & 1023);   // src:17b | dst_lo:10b
    }
}

// ---------------- pass 2: per-bucket counting sort -> esrc, row_start, dinv ----------------
__global__ __launch_bounds__(256) void k_csr(const int* __restrict__ tmp, const int* __restrict__ gbase,
                                             int* __restrict__ esrc, int* __restrict__ row_start,
                                             float* __restrict__ dinv) {
    __shared__ int h[1024], hs[1024], part[256];
    int b = blockIdx.x, t = threadIdx.x;
    int base = gbase[b], end = gbase[b + 1];
#pragma unroll
    for (int k = 0; k < 4; ++k) h[t * 4 + k] = 0;
    __syncthreads();
    for (int i = base + t; i < end; i += 256) atomicAdd(&h[tmp[i] & 1023], 1);
    __syncthreads();
    int l0 = h[t * 4], l1 = h[t * 4 + 1], l2 = h[t * 4 + 2], l3 = h[t * 4 + 3];
    int ssum = l0 + l1 + l2 + l3;
    part[t] = ssum;
    __syncthreads();
    for (int o = 1; o < 256; o <<= 1) {
        int a = (t >= o) ? part[t - o] : 0;
        __syncthreads();
        part[t] += a;
        __syncthreads();
    }
    int ex = part[t] - ssum;
    hs[t * 4]     = ex;
    hs[t * 4 + 1] = ex + l0;
    hs[t * 4 + 2] = ex + l0 + l1;
    hs[t * 4 + 3] = ex + l0 + l1 + l2;
    int n0 = b * 1024 + t * 4;
#pragma unroll
    for (int k = 0; k < 4; ++k) {
        int n = n0 + k;
        if (n < NN) {
            row_start[n] = base + hs[t * 4 + k];
            dinv[n] = rsqrtf((float)h[t * 4 + k] + 1.0f);
        }
    }
    __syncthreads();
    for (int i = base + t; i < end; i += 256) {
        int rec = tmp[i];
        int pos = atomicAdd(&hs[rec & 1023], 1);
        esrc[base + pos] = rec >> 10;
    }
}

// ---------------- merged: BN finalize (block 0) + W-scale for next layer (blocks 1..32) ----------------
__global__ __launch_bounds__(128) void k_finwscale(const float* __restrict__ S, const float* __restrict__ Q,
                                                   const float* __restrict__ gam, const float* __restrict__ bet,
                                                   float* __restrict__ svec, float* __restrict__ tvec,
                                                   const float* __restrict__ Wnext, float* __restrict__ tW,
                                                   const ushort* __restrict__ Wfb, ushort* __restrict__ Wff) {
    int bid = blockIdx.x;
    int t = threadIdx.x;
    if (bid == 0) {
        __shared__ float ts[128];
        float s = 0.f, q = 0.f;
        for (int k = 0; k < NBKT; ++k) {
            s += S[k * 128 + t];
            q += Q[k * 128 + t];
        }
        float mean = s / (float)NN;
        float var = q / (float)NN - mean * mean;
        float rstd = rsqrtf(fmaxf(var, 0.f) + BN_EPS);
        float sc = gam[t] * rstd;
        float sh = bet[t] - mean * sc;
        svec[t] = sc;
        tvec[t] = sh;
        ts[t] = sh;
        __syncthreads();
        if (Wnext) {
            float acc = 0.f;
            for (int k = 0; k < 128; ++k) acc += ts[k] * Wnext[(size_t)k * 128 + t];
            tW[t] = acc;
        }
    } else {
        __shared__ float sv[32];
        int unit = bid - 1;
        int kbase = (unit >> 3) * 32;
        if (t < 32) {
            int c = kbase + t;
            float s = 0.f, q = 0.f;
            for (int k = 0; k < NBKT; ++k) {
                s += S[k * 128 + c];
                q += Q[k * 128 + c];
            }
            float mean = s / (float)NN;
            float var = q / (float)NN - mean * mean;
            sv[t] = gam[c] * rsqrtf(fmaxf(var, 0.f) + BN_EPS);
        }
        __syncthreads();
        if (t < 64) {
            int ko = (t >> 4) * 8;   // offset within the 32-k window
            const ushort* p = Wfb + ((size_t)unit * 64 + t) * 8;
            ushort* o = Wff + ((size_t)unit * 64 + t) * 8;
#pragma unroll
            for (int j = 0; j < 8; ++j) o[j] = f2bf(bf2f(p[j]) * sv[ko + j]);
        }
    }
}

// ---------------- MFMA GEMM (pure): hm'[N][128] = dinv[row] * (X @ Wf + tW) ----------------
// X source: xf32 (layer 0, packs fragments in-register) or Xb bf16 (layers 1,2)
__global__ __launch_bounds__(256) void k_gemm(const ushort* __restrict__ Xb, const float* __restrict__ xf32,
                                              const ushort* __restrict__ Wf, const float* __restrict__ tW,
                                              const float* __restrict__ dinv, ushort* __restrict__ hm) {
    int tid = threadIdx.x;
    int wid = tid >> 6, lane = tid & 63;
    int r0 = blockIdx.x * 64 + wid * 16;
    int m = lane & 15, g = lane >> 4;
    int xrow = r0 + m;
    int xr = (xrow < NN) ? xrow : (NN - 1);
    s16x8 af[4];
    if (xf32) {
        const float* Xr = xf32 + (size_t)xr * 128 + g * 8;
#pragma unroll
        for (int ks = 0; ks < 4; ++ks) {
            float4 a = *(const float4*)(Xr + ks * 32);
            float4 b = *(const float4*)(Xr + ks * 32 + 4);
            s16x8 v;
            v[0] = (short)f2bf(a.x); v[1] = (short)f2bf(a.y);
            v[2] = (short)f2bf(a.z); v[3] = (short)f2bf(a.w);
            v[4] = (short)f2bf(b.x); v[5] = (short)f2bf(b.y);
            v[6] = (short)f2bf(b.z); v[7] = (short)f2bf(b.w);
            af[ks] = v;
        }
    } else {
        const ushort* Xrow = Xb + (size_t)xr * 128 + g * 8;
#pragma unroll
        for (int ks = 0; ks < 4; ++ks) af[ks] = *(const s16x8*)(Xrow + ks * 32);
    }
    f32x4 acc[8];
#pragma unroll
    for (int nb = 0; nb < 8; ++nb) acc[nb] = (f32x4){0.f, 0.f, 0.f, 0.f};
#pragma unroll
    for (int ks = 0; ks < 4; ++ks) {
#pragma unroll
        for (int nb = 0; nb < 8; ++nb) {
            s16x8 wf = *(const s16x8*)(Wf + ((size_t)(ks * 8 + nb) * 64 + lane) * 8);
            acc[nb] = __builtin_amdgcn_mfma_f32_16x16x32_bf16(wf, af[ks], acc[nb], 0, 0, 0);
        }
    }
    if (xrow < NN) {
        float ds = dinv[xr];
        ushort* orow = hm + (size_t)xrow * 128 + g * 4;
        if (tW) {
#pragma unroll
            for (int nb = 0; nb < 8; ++nb) {
                float4 tw = *(const float4*)(tW + nb * 16 + g * 4);
                ushort4 o;
                o.x = f2bf(ds * (acc[nb][0] + tw.x));
                o.y = f2bf(ds * (acc[nb][1] + tw.y));
                o.z = f2bf(ds * (acc[nb][2] + tw.z));
                o.w = f2bf(ds * (acc[nb][3] + tw.w));
                *(ushort4*)(orow + nb * 16) = o;
            }
        } else {
#pragma unroll
            for (int nb = 0; nb < 8; ++nb) {
                ushort4 o;
                o.x = f2bf(ds * acc[nb][0]);
                o.y = f2bf(ds * acc[nb][1]);
                o.z = f2bf(ds * acc[nb][2]);
                o.w = f2bf(ds * acc[nb][3]);
                *(ushort4*)(orow + nb * 16) = o;
            }
        }
    }
}

// ---------------- aggregate + bias + relu + fused BN stats (round-10 exact form) ----------------
__global__ __launch_bounds__(256) void k_agg(const uint* __restrict__ hm32, const int* __restrict__ esrc,
                                             const int* __restrict__ rs, const float* __restrict__ dinv,
                                             const float* __restrict__ bias, uint* __restrict__ act,
                                             float* __restrict__ bnsum, float* __restrict__ bnsq) {
    __shared__ float ls[128], lq[128];
    int tid = threadIdx.x;
    if (tid < 128) { ls[tid] = 0.f; lq[tid] = 0.f; }
    __syncthreads();
    int lane = tid & 63;
    int wgid = blockIdx.x * 4 + (tid >> 6);
    float2 b2 = *(const float2*)(bias + lane * 2);
    float s0 = 0.f, s1 = 0.f, q0 = 0.f, q1 = 0.f;

    for (int n = wgid; n < NN; n += AGG_WAVES) {
        uint self = hm32[(size_t)n * 64 + lane];
        float a0 = bf_lo(self);
        float a1 = bf_hi(self);

        int i  = __builtin_amdgcn_readfirstlane(rs[n]);
        int i1 = __builtin_amdgcn_readfirstlane(rs[n + 1]);

        int idxv = 0;
        if (i < i1) idxv = esrc[i + min(min(lane, 15), i1 - i - 1)];

        while (i < i1) {
            int cnt = i1 - i;
            cnt = (cnt > 16) ? 16 : cnt;       // wave-uniform
            int cur = idxv;
            int inext = i + cnt;
            if (inext < i1)                    // prefetch next chunk while gathers fly
                idxv = esrc[inext + min(min(lane, 15), i1 - inext - 1)];
            uint g[16];
#pragma unroll
            for (int u = 0; u < 16; ++u) {
                int sidx = __builtin_amdgcn_readlane(cur, u);
                sidx = (u < cnt) ? sidx : NN;  // scalar select -> zero row for pads
                g[u] = hm32[(size_t)sidx * 64 + lane];
            }
#pragma unroll
            for (int u = 0; u < 16; ++u) {
                a0 += bf_lo(g[u]);
                a1 += bf_hi(g[u]);
            }
            i = inext;
        }
        float di = dinv[n];
        float z0 = fmaxf(fmaf(di, a0, b2.x), 0.f);
        float z1 = fmaxf(fmaf(di, a1, b2.y), 0.f);
        act[(size_t)n * 64 + lane] = packbf(z0, z1);
        s0 += z0; s1 += z1;
        q0 += z0 * z0; q1 += z1 * z1;
    }
    atomicAdd(&ls[lane * 2],     s0);
    atomicAdd(&ls[lane * 2 + 1], s1);
    atomicAdd(&lq[lane * 2],     q0);
    atomicAdd(&lq[lane * 2 + 1], q1);
    __syncthreads();
    if (tid < 128) {
        int bkt = blockIdx.x & (NBKT - 1);
        atomicAdd(&bnsum[bkt * 128 + tid], ls[tid]);
        atomicAdd(&bnsq[bkt * 128 + tid],  lq[tid]);
    }
}

// ---------------- per-graph pool + h_cat out-write ----------------
__global__ __launch_bounds__(128) void k_pool(const uint* __restrict__ act32, const float* __restrict__ svec,
                                              const float* __restrict__ tvec, const int* __restrict__ batch,
                                              float* __restrict__ gout, float* __restrict__ outp, int lofs) {
    int t = threadIdx.x;
    int lane = t & 63;
    int w = t >> 6;
    int n0 = blockIdx.x * 64;
    float sc0 = svec[lane * 2], sc1 = svec[lane * 2 + 1];
    float sh0 = tvec[lane * 2], sh1 = tvec[lane * 2 + 1];
    float s0 = 0.f, s1 = 0.f;
    int cnt = 0, curg = -1;
    for (int k = w; k < 64; k += 2) {
        int n = n0 + k;
        if (n >= NN) break;
        int gn = batch[n];
        if (gn != curg) {
            if (cnt) {
                atomicAdd(&gout[(size_t)curg * 384 + lofs + lane * 2],     sc0 * s0 + sh0 * (float)cnt);
                atomicAdd(&gout[(size_t)curg * 384 + lofs + lane * 2 + 1], sc1 * s1 + sh1 * (float)cnt);
            }
            curg = gn; s0 = 0.f; s1 = 0.f; cnt = 0;
        }
        uint v = act32[(size_t)n * 64 + lane];
        float a0 = bf_lo(v), a1 = bf_hi(v);
        float2 z;
        z.x = a0 * sc0 + sh0;
        z.y = a1 * sc1 + sh1;
        *(float2*)(outp + (size_t)n * 384 + lofs + lane * 2) = z;
        s0 += a0;
        s1 += a1;
        ++cnt;
    }
    if (cnt) {
        atomicAdd(&gout[(size_t)curg * 384 + lofs + lane * 2],     sc0 * s0 + sh0 * (float)cnt);
        atomicAdd(&gout[(size_t)curg * 384 + lofs + lane * 2 + 1], sc1 * s1 + sh1 * (float)cnt);
    }
}

extern "C" void kernel_launch(void* const* d_in, const int* in_sizes, int n_in,
                              void* d_out, int out_size, void* d_ws, size_t ws_size,
                              hipStream_t stream) {
    const float* x = (const float*)d_in[0];
    const int* ei = (const int*)d_in[1];
    const int* src = ei;
    const int* dst = ei + NE;
    const int* batch = (const int*)d_in[2];
    const float *W[3], *b[3], *g[3], *beta[3];
    for (int l = 0; l < 3; ++l) {
        W[l]    = (const float*)d_in[3 + 4 * l];
        b[l]    = (const float*)d_in[4 + 4 * l];
        g[l]    = (const float*)d_in[5 + 4 * l];
        beta[l] = (const float*)d_in[6 + 4 * l];
    }
    float* out = (float*)d_out;
    float* gout = out + (size_t)NN * 384;

    char* ws = (char*)d_ws;
    size_t off = 0;
    auto alloc = [&](size_t bytes) -> char* {
        off = (off + 255) & ~(size_t)255;
        char* p = ws + off;
        off += bytes;
        return p;
    };
    ushort* act      = (ushort*)alloc((size_t)NN * 256);        // bf16 relu output (pre-BN)
    ushort* hm       = (ushort*)alloc((size_t)(NN + 1) * 256);  // bf16 hm' rows + zero row at NN
    int*    esrc     = (int*)alloc((size_t)NE * 4);
    int*    tmp      = (int*)alloc((size_t)NE * 4);
    int*    row_start= (int*)alloc((size_t)(NN + 1) * 4);
    float*  dinv     = (float*)alloc((size_t)NN * 4);
    float*  bnst     = (float*)alloc((size_t)3 * 2 * NBKT * 128 * 4);   // [layer][sum|sq][NBKT][128]
    ushort* Wf       = (ushort*)alloc(3 * 16384 * 2);
    ushort* Wff      = (ushort*)alloc(16384 * 2);
    float*  svt      = (float*)alloc(3 * 2 * 128 * 4);                  // [layer][s|t][128]
    float*  tW       = (float*)alloc(128 * 4);
    int*    misc     = (int*)alloc(1024 * 4);   // gbh[128], gbase[129], gcur[128], ticks[8]
    int* gbh   = misc;
    int* gbase = misc + 128;
    int* gcur  = misc + 384;
    int* ticks = misc + 512;
    uint* hmz  = (uint*)(hm + (size_t)NN * 128);
    (void)ws_size;

    // 16 dispatches, no memsets
    k_setup<<<481, 256, 0, stream>>>(W[0], W[1], W[2], Wf, gbh, ticks, bnst, gout, hmz);
    k_bhist<<<512, 256, 0, stream>>>(dst, gbh, gbase, gcur, row_start, ticks);
    k_bin<<<BIN_BLOCKS, 256, 0, stream>>>(src, dst, gcur, tmp);
    k_csr<<<NBUCK, 256, 0, stream>>>(tmp, gbase, esrc, row_start, dinv);

    for (int l = 0; l < 3; ++l) {
        float* S = bnst + (size_t)l * 2 * NBKT * 128;
        float* Q = S + NBKT * 128;
        float* sv = svt + l * 256;
        float* tv = sv + 128;
        const ushort* gin = (l == 0) ? (const ushort*)nullptr : act;
        const float* xin = (l == 0) ? x : nullptr;
        const ushort* wfrag = (l == 0) ? (Wf + 0) : Wff;
        const float* tw_in = (l == 0) ? nullptr : tW;
        const float* wnp = (l < 2) ? W[l + 1] : nullptr;
        const ushort* wfbp = (l < 2) ? (Wf + (size_t)(l + 1) * 16384) : nullptr;

        k_gemm<<<(NN + 63) / 64, 256, 0, stream>>>(gin, xin, wfrag, tw_in, dinv, hm);
        k_agg<<<AGG_BLOCKS, 256, 0, stream>>>((const uint*)hm, esrc, row_start, dinv, b[l],
                                              (uint*)act, S, Q);
        k_finwscale<<<(l < 2) ? 33 : 1, 128, 0, stream>>>(S, Q, g[l], beta[l], sv, tv,
                                                          wnp, tW, wfbp, Wff);
        k_pool<<<(NN + 63) / 64, 128, 0, stream>>>((const uint*)act, sv, tv, batch, gout, out, l * 128);
    }
}